// Round 12
// baseline (81.781 us; speedup 1.0000x reference)
//
#include <hip/hip_runtime.h>
#include <math.h>

#define BB 4
#define NN 6
#define DD 41
#define CC 64
#define FHh 16
#define FWw 44
#define NXg 200
#define NYg 200
#define NZg 1
#define NSLOT 128
#define NOVF  (FHh*DD)                 // 656 worst-case points per column
#define XYg (NXg*NYg)                  // 40000
#define NVOX (BB*NZg*NXg*NYg)          // 160000
#define NCOL (BB*NN*FWw)               // 1056 columns
#define NPIX (BB*NN*FHh*FWw)           // 16896
#define NCH  (DD+CC)                   // 105
#define NTILE (NVOX/64)                // 2500
#define CAP   1024                     // tile list capacity
#define MAXR  (NCOL*NSLOT)             // 135168 record ids
#define MAXOV2 65536

// ---- ws byte offsets ----
#define TCNT_OFF  0u                           // 2500 ints
#define OC1_OFF   10240u
#define OC2_OFF   10244u
#define MEMZ      16384u                       // one memset covers all above
#define VOXL_OFF  16384u                       // MAXR ints        = 540672
#define FT_OFF    557056u                      // NCOL*16*64 f     = 4325376
#define COEF_OFF  4882432u                     // MAXR*16 f        = 8650752
#define TLIST_OFF 13533184u                    // NTILE*CAP ints   = 10240000
#define OVF1_OFF  23773184u                    // MAXR ints        = 540672
#define OVF2_OFF  24313856u                    // MAXOV2 int4      = 1048576
#define WS_NEED   25362432u                    // ~25.4 MB

__device__ __forceinline__ void inv3x3d(const double m[9], double o[9]) {
    double a=m[0],b=m[1],c=m[2],d=m[3],e=m[4],f=m[5],g=m[6],h=m[7],i=m[8];
    double A = e*i - f*h;
    double Bv = -(d*i - f*g);
    double Cv = d*h - e*g;
    double det = a*A + b*Bv + c*Cv;
    double r = 1.0/det;
    o[0]=A*r;  o[1]=-(b*i-c*h)*r; o[2]=(b*f-c*e)*r;
    o[3]=Bv*r; o[4]=(a*i-c*g)*r;  o[5]=-(a*f-c*d)*r;
    o[6]=Cv*r; o[7]=-(a*h-b*g)*r; o[8]=(a*e-b*d)*r;
}

__global__ __launch_bounds__(256)
void lss_zero(float4* __restrict__ p, int n4)
{
    const int stride = gridDim.x * 256;
    for (int i = blockIdx.x * 256 + threadIdx.x; i < n4; i += stride)
        p[i] = make_float4(0.f, 0.f, 0.f, 0.f);
}

// --------- Phase A: per-column dedup -> records + per-tile bin lists --------
__global__ __launch_bounds__(256)
void lss_build2(const float* __restrict__ xf,
                const float* __restrict__ rots,
                const float* __restrict__ trans,
                const float* __restrict__ intr,
                const float* __restrict__ prots,
                const float* __restrict__ ptrans,
                char* __restrict__ wsb)
{
    int*   tcnt = (int*)  (wsb + TCNT_OFF);
    int*   oc1  = (int*)  (wsb + OC1_OFF);
    int*   oc2  = (int*)  (wsb + OC2_OFF);
    int*   voxl = (int*)  (wsb + VOXL_OFF);
    float* fT   = (float*)(wsb + FT_OFF);
    float* coefG= (float*)(wsb + COEF_OFF);
    int*   tlist= (int*)  (wsb + TLIST_OFF);
    int*   ovf1 = (int*)  (wsb + OVF1_OFF);
    int4*  ovf2 = (int4*) (wsb + OVF2_OFF);

    __shared__ float s_lg[FHh * FWw];        // logits [h][d] stride 44
    __shared__ float s_feat[FHh * CC];       // feats  [h][c]
    __shared__ float s_coef[NSLOT * 17];     // [slot][h] pad 17
    __shared__ int   s_keys[NSLOT];
    __shared__ short s_list[NSLOT];
    __shared__ int   s_nslot;
    __shared__ int2  s_ovf[NOVF];
    __shared__ float s_ovfw[NOVF];
    __shared__ int   s_ovfcnt;

    const int tid  = threadIdx.x;
    const int lane = tid & 63;
    const int wv   = tid >> 6;          // 0..3

    // XCD swizzle: 1056 = 8*132
    const int obid = blockIdx.x;
    const int bid  = (obid & 7) * (NCOL / 8) + (obid >> 3);
    const int w   = bid % FWw;
    const int rem = bid / FWw;
    const int n   = rem % NN;
    const int b   = rem / NN;
    const int cam = b*NN + n;
    const float* colbase = xf + (size_t)cam * NCH * FHh * FWw + w;

    if (tid < NSLOT) s_keys[tid] = -1;
    for (int i = tid; i < NSLOT*17; i += 256) s_coef[i] = 0.0f;
    if (tid == 0) { s_nslot = 0; s_ovfcnt = 0; }

    // stage the whole column (1680 scalars, strided)
    for (int t = tid; t < NCH*FHh; t += 256) {
        int h  = t / NCH;
        int ch = t - h*NCH;
        float v = colbase[(size_t)ch * (FHh*FWw) + h * FWw];
        if (ch < DD) s_lg[h*FWw + ch] = v;
        else         s_feat[(h << 6) + (ch - DD)] = v;
    }

    // per-camera transform (f64, redundant per thread)
    double K9[9], P9[9], R9[9];
    #pragma unroll
    for (int i = 0; i < 9; ++i) {
        K9[i] = (double)intr [cam*9 + i];
        P9[i] = (double)prots[cam*9 + i];
        R9[i] = (double)rots [cam*9 + i];
    }
    double Kinv[9], Pinv[9];
    inv3x3d(K9, Kinv);
    inv3x3d(P9, Pinv);
    double M[9];
    #pragma unroll
    for (int i = 0; i < 3; ++i)
        #pragma unroll
        for (int j = 0; j < 3; ++j)
            M[i*3+j] = R9[i*3+0]*Kinv[0*3+j] + R9[i*3+1]*Kinv[1*3+j] + R9[i*3+2]*Kinv[2*3+j];
    const double tx  = (double)trans [cam*3+0], ty  = (double)trans [cam*3+1], tz  = (double)trans [cam*3+2];
    const double ptx = (double)ptrans[cam*3+0], pty = (double)ptrans[cam*3+1], ptz = (double)ptrans[cam*3+2];

    __syncthreads();

    // softmax + geometry + hash insert; wave wv handles h = 4wv..4wv+3
    int      last_vox  = -1;
    unsigned last_slot = 0;
    for (int r = 0; r < 4; ++r) {
        const int h = (wv << 2) + r;
        float logit = (lane < DD) ? s_lg[h*FWw + lane] : -INFINITY;
        float mx = logit;
        #pragma unroll
        for (int off = 32; off; off >>= 1) mx = fmaxf(mx, __shfl_xor(mx, off));
        float ex = (lane < DD) ? expf(logit - mx) : 0.0f;
        float sm = ex;
        #pragma unroll
        for (int off = 32; off; off >>= 1) sm += __shfl_xor(sm, off);
        const float wgt = ex / sm;

        int vox = -1;
        if (lane < DD) {
            double dz = 4.0 + (double)lane;
            double xs = (double)w * (703.0/43.0);
            double ys = (double)h * 17.0;
            double px = xs - ptx, py = ys - pty, pz = dz - ptz;
            double qx = Pinv[0]*px + Pinv[1]*py + Pinv[2]*pz;
            double qy = Pinv[3]*px + Pinv[4]*py + Pinv[5]*pz;
            double qz = Pinv[6]*px + Pinv[7]*py + Pinv[8]*pz;
            qx *= qz; qy *= qz;
            double gx = M[0]*qx + M[1]*qy + M[2]*qz + tx;
            double gy = M[3]*qx + M[4]*qy + M[5]*qz + ty;
            double gz = M[6]*qx + M[7]*qy + M[8]*qz + tz;
            double fx = floor((gx + 50.0) / 0.5);
            double fy = floor((gy + 50.0) / 0.5);
            double fz = floor((gz + 10.0) / 20.0);
            if (fx >= 0.0 && fx < (double)NXg &&
                fy >= 0.0 && fy < (double)NYg &&
                fz >= 0.0 && fz < (double)NZg) {
                int ix = (int)fx, iy = (int)fy, iz = (int)fz;
                vox = ((b*NZg + iz)*NXg + ix)*NYg + iy;
            }
        }

        if (vox >= 0) {
            if (vox == last_vox) {
                atomicAdd(&s_coef[last_slot*17 + h], wgt);
            } else {
                unsigned slot = (((unsigned)vox * 2654435761u) >> 18) & (NSLOT-1);
                bool done = false;
                for (int probe = 0; probe < NSLOT; ++probe) {
                    int prev = atomicCAS(&s_keys[slot], -1, vox);
                    if (prev == -1) {
                        int k = atomicAdd(&s_nslot, 1);
                        s_list[k] = (short)slot;
                    }
                    if (prev == -1 || prev == vox) {
                        atomicAdd(&s_coef[slot*17 + h], wgt);
                        last_vox = vox; last_slot = slot;
                        done = true;
                        break;
                    }
                    slot = (slot + 1) & (NSLOT-1);
                }
                if (!done) {
                    int k = atomicAdd(&s_ovfcnt, 1);
                    s_ovf[k]  = make_int2(vox, h);
                    s_ovfw[k] = wgt;
                    last_vox = -1;
                }
            }
        }
    }

    __syncthreads();

    const int nocc = s_nslot;
    const int novf = s_ovfcnt;

    // publish features fT[bid][h][c] (coalesced)
    {
        float* ft = fT + (size_t)bid * (FHh*CC);
        for (int i = tid; i < FHh*CC; i += 256) ft[i] = s_feat[i];
    }
    // publish voxel ids + coefficients (coalesced)
    for (int e = tid; e < nocc; e += 256)
        voxl[bid*NSLOT + e] = s_keys[s_list[e]];
    for (int i = tid; i < nocc*16; i += 256) {
        int e = i >> 4, hh = i & 15;
        coefG[((size_t)bid*NSLOT + e)*16 + hh] = s_coef[s_list[e]*17 + hh];
    }
    // bin each record into its output tile's list (one atomic per record)
    for (int e = tid; e < nocc; e += 256) {
        int vox  = s_keys[s_list[e]];
        int tile = vox >> 6;
        int rid  = bid*NSLOT + e;
        int pos  = atomicAdd(&tcnt[tile], 1);
        if (pos < CAP) tlist[(size_t)tile*CAP + pos] = rid;
        else { int k = atomicAdd(oc1, 1); if (k < MAXR) ovf1[k] = rid; }
    }
    // hash-table-full overflow (rare): raw (vox,bid,h,wgt) quads
    for (int e = tid; e < novf; e += 256) {
        int k = atomicAdd(oc2, 1);
        if (k < MAXOV2) {
            int4 q;
            q.x = s_ovf[e].x; q.y = bid; q.z = s_ovf[e].y;
            q.w = __float_as_int(s_ovfw[e]);
            ovf2[k] = q;
        }
    }
}

// --------- Phase B: one block per 64-cell tile; dense final write -----------
__global__ __launch_bounds__(256)
void lss_tile(const char* __restrict__ wsb, float* __restrict__ out)
{
    const int*   tcnt = (const int*)  (wsb + TCNT_OFF);
    const int*   voxl = (const int*)  (wsb + VOXL_OFF);
    const float* fT   = (const float*)(wsb + FT_OFF);
    const float* coefG= (const float*)(wsb + COEF_OFF);
    const int*   tlist= (const int*)  (wsb + TLIST_OFF);

    __shared__ float acc[CC * 65];           // [c][cell] pad 65
    const int t    = blockIdx.x;             // 0..2499
    const int bz   = t / 625;
    const int xy0  = (t % 625) * 64;
    const int tid  = threadIdx.x;
    const int lane = tid & 63;               // = channel c
    const int wv   = tid >> 6;

    for (int i = tid; i < CC*65; i += 256) acc[i] = 0.0f;
    __syncthreads();

    const int n = min(tcnt[t], CAP);
    for (int i = wv; i < n; i += 4) {
        int rid  = tlist[(size_t)t*CAP + i];
        int vox  = voxl[rid];
        int cell = vox & 63;
        int colb = rid >> 7;                 // NSLOT=128
        const float* cf = coefG + (size_t)rid * 16;
        const float* fb = fT + (size_t)colb * (FHh*CC) + lane;
        float a = 0.0f;
        #pragma unroll
        for (int h = 0; h < FHh; ++h)
            a += cf[h] * fb[h << 6];
        atomicAdd(&acc[lane*65 + cell], a);  // banks (c+cell)%32: 2-way, free
    }
    __syncthreads();

    float* dst = out + (size_t)bz * CC * XYg + xy0;
    #pragma unroll
    for (int rep = 0; rep < 4; ++rep) {
        int c = (wv << 4) + (rep << 2) + (lane >> 4);
        int q = lane & 15;
        float4 v = make_float4(acc[c*65 + 4*q + 0], acc[c*65 + 4*q + 1],
                               acc[c*65 + 4*q + 2], acc[c*65 + 4*q + 3]);
        ((float4*)(dst + (size_t)c * XYg))[q] = v;
    }
}

// --------- Phase C: rare overflow records, atomics after dense write --------
__global__ __launch_bounds__(256)
void lss_ovf(const char* __restrict__ wsb, float* __restrict__ out)
{
    const int*   oc1  = (const int*)  (wsb + OC1_OFF);
    const int*   oc2  = (const int*)  (wsb + OC2_OFF);
    const int*   voxl = (const int*)  (wsb + VOXL_OFF);
    const float* fT   = (const float*)(wsb + FT_OFF);
    const float* coefG= (const float*)(wsb + COEF_OFF);
    const int*   ovf1 = (const int*)  (wsb + OVF1_OFF);
    const int4*  ovf2 = (const int4*) (wsb + OVF2_OFF);

    const int lane = threadIdx.x & 63;
    const int wv   = threadIdx.x >> 6;

    const int n1 = min(*oc1, MAXR);
    for (int i = wv; i < n1; i += 4) {
        int rid = ovf1[i];
        int vox = voxl[rid];
        int colb = rid >> 7;
        const float* cf = coefG + (size_t)rid * 16;
        const float* fb = fT + (size_t)colb * (FHh*CC) + lane;
        float a = 0.0f;
        #pragma unroll
        for (int h = 0; h < FHh; ++h) a += cf[h] * fb[h << 6];
        int bz = vox / XYg, xy = vox - bz * XYg;
        atomicAdd(&out[(size_t)bz * CC * XYg + (size_t)lane * XYg + xy], a);
    }
    const int n2 = min(*oc2, MAXOV2);
    for (int i = wv; i < n2; i += 4) {
        int4 q = ovf2[i];
        int vox = q.x, bidc = q.y, h = q.z;
        float wgt = __int_as_float(q.w);
        float f = fT[(size_t)bidc * (FHh*CC) + (h << 6) + lane];
        int bz = vox / XYg, xy = vox - bz * XYg;
        atomicAdd(&out[(size_t)bz * CC * XYg + (size_t)lane * XYg + xy], wgt * f);
    }
}

// ---------------- fallback (tiny ws): zero out + direct atomics -------------
__global__ __launch_bounds__(256)
void lss_scatter_direct(const float* __restrict__ xf,
                        const float* __restrict__ rots,
                        const float* __restrict__ trans,
                        const float* __restrict__ intr,
                        const float* __restrict__ prots,
                        const float* __restrict__ ptrans,
                        float* __restrict__ acc)
{
    const int wid  = blockIdx.x * 4 + (threadIdx.x >> 6);
    const int lane = threadIdx.x & 63;
    if (wid >= NPIX) return;
    int w  = wid % FWw;
    int t1 = wid / FWw;
    int h  = t1 % FHh; t1 /= FHh;
    int n  = t1 % NN;
    int b  = t1 / NN;
    const int cam = b*NN + n;

    double K9[9], P9[9], R9[9];
    #pragma unroll
    for (int i = 0; i < 9; ++i) {
        K9[i] = (double)intr [cam*9 + i];
        P9[i] = (double)prots[cam*9 + i];
        R9[i] = (double)rots [cam*9 + i];
    }
    double Kinv[9], Pinv[9];
    inv3x3d(K9, Kinv);
    inv3x3d(P9, Pinv);
    double M[9];
    #pragma unroll
    for (int i = 0; i < 3; ++i)
        #pragma unroll
        for (int j = 0; j < 3; ++j)
            M[i*3+j] = R9[i*3+0]*Kinv[0*3+j] + R9[i*3+1]*Kinv[1*3+j] + R9[i*3+2]*Kinv[2*3+j];
    const double tx  = (double)trans [cam*3+0], ty  = (double)trans [cam*3+1], tz  = (double)trans [cam*3+2];
    const double ptx = (double)ptrans[cam*3+0], pty = (double)ptrans[cam*3+1], ptz = (double)ptrans[cam*3+2];

    const size_t pixoff = (size_t)cam * NCH * FHh * FWw + (size_t)h * FWw + w;
    float logit = (lane < DD) ? xf[pixoff + (size_t)lane * (FHh*FWw)] : -INFINITY;
    float mx = logit;
    #pragma unroll
    for (int off = 32; off; off >>= 1) mx = fmaxf(mx, __shfl_xor(mx, off));
    float ex = (lane < DD) ? expf(logit - mx) : 0.0f;
    float sm = ex;
    #pragma unroll
    for (int off = 32; off; off >>= 1) sm += __shfl_xor(sm, off);
    const float wgt = ex / sm;

    int baddr = -1;
    if (lane < DD) {
        double dz = 4.0 + (double)lane;
        double xs = (double)w * (703.0/43.0);
        double ys = (double)h * 17.0;
        double px = xs - ptx, py = ys - pty, pz = dz - ptz;
        double qx = Pinv[0]*px + Pinv[1]*py + Pinv[2]*pz;
        double qy = Pinv[3]*px + Pinv[4]*py + Pinv[5]*pz;
        double qz = Pinv[6]*px + Pinv[7]*py + Pinv[8]*pz;
        qx *= qz; qy *= qz;
        double gx = M[0]*qx + M[1]*qy + M[2]*qz + tx;
        double gy = M[3]*qx + M[4]*qy + M[5]*qz + ty;
        double gz = M[6]*qx + M[7]*qy + M[8]*qz + tz;
        double fx = floor((gx + 50.0) / 0.5);
        double fy = floor((gy + 50.0) / 0.5);
        double fz = floor((gz + 10.0) / 20.0);
        if (fx >= 0.0 && fx < (double)NXg &&
            fy >= 0.0 && fy < (double)NYg &&
            fz >= 0.0 && fz < (double)NZg) {
            int ix = (int)fx, iy = (int)fy, iz = (int)fz;
            int bz = b*NZg + iz;
            baddr = bz * (CC*XYg) + ix*NYg + iy;
        }
    }

    const float f = xf[pixoff + (size_t)(DD + lane) * (FHh*FWw)];
    for (int d = 0; d < DD; ++d) {
        int   a  = __shfl(baddr, d);
        float wd = __shfl(wgt,   d);
        if (a >= 0) atomicAdd(&acc[(size_t)a + (size_t)lane * XYg], wd * f);
    }
}

extern "C" void kernel_launch(void* const* d_in, const int* in_sizes, int n_in,
                              void* d_out, int out_size, void* d_ws, size_t ws_size,
                              hipStream_t stream) {
    const float* xf     = (const float*)d_in[0];
    const float* rots   = (const float*)d_in[1];
    const float* trans  = (const float*)d_in[2];
    const float* intr   = (const float*)d_in[3];
    const float* prots  = (const float*)d_in[4];
    const float* ptrans = (const float*)d_in[5];
    float* out = (float*)d_out;

    if (ws_size >= (size_t)WS_NEED) {
        char* wsb = (char*)d_ws;
        hipMemsetAsync(wsb, 0, MEMZ, stream);   // tile counters + ovf counters
        lss_build2<<<dim3(NCOL), dim3(256), 0, stream>>>(
            xf, rots, trans, intr, prots, ptrans, wsb);
        lss_tile<<<dim3(NTILE), dim3(256), 0, stream>>>(wsb, out);
        lss_ovf<<<dim3(1), dim3(256), 0, stream>>>(wsb, out);
    } else {
        lss_zero<<<dim3(2048), dim3(256), 0, stream>>>(
            (float4*)out, (BB*NZg*XYg*CC)/4);
        lss_scatter_direct<<<dim3((NPIX + 3) / 4), dim3(256), 0, stream>>>(
            xf, rots, trans, intr, prots, ptrans, out);
    }
}

// Round 14
// 46.233 us; speedup vs baseline: 1.7689x; 1.7689x over previous
//
#include <hip/hip_runtime.h>
#include <math.h>

#define BB 4
#define NN 6
#define DD 41
#define CC 64
#define FHh 16
#define FWw 44
#define NXg 200
#define NYg 200
#define NZg 1
#define NSLOT 128
#define NOVF  (FHh*DD)                 // 656 worst-case points per column
#define XYg (NXg*NYg)                  // 40000
#define NVOX (BB*NZg*NXg*NYg)          // 160000
#define NCOL (BB*NN*FWw)               // 1056 columns
#define NPIX (BB*NN*FHh*FWw)           // 16896
#define NCH  (DD+CC)                   // 105
#define NTILE (NVOX/64)                // 2500

// ws layout: wsv[NVOX][CC] floats, then byte map bmap[NVOX]
#define WSV_BYTES  (NVOX*CC*4u)        // 40,960,000
#define BMAP_OFF   WSV_BYTES
#define ZERO_BYTES (WSV_BYTES + (unsigned)NVOX)   // 41,120,000 (16B multiple)
#define WS_NEED    ZERO_BYTES

__device__ __forceinline__ void inv3x3d(const double m[9], double o[9]) {
    double a=m[0],b=m[1],c=m[2],d=m[3],e=m[4],f=m[5],g=m[6],h=m[7],i=m[8];
    double A = e*i - f*h;
    double Bv = -(d*i - f*g);
    double Cv = d*h - e*g;
    double det = a*A + b*Bv + c*Cv;
    double r = 1.0/det;
    o[0]=A*r;  o[1]=-(b*i-c*h)*r; o[2]=(b*f-c*e)*r;
    o[3]=Bv*r; o[4]=(a*i-c*g)*r;  o[5]=-(a*f-c*d)*r;
    o[6]=Cv*r; o[7]=-(a*h-b*g)*r; o[8]=(a*e-b*d)*r;
}

// fast zero-fill: grid-stride float4 (covers wsv + bmap)
__global__ __launch_bounds__(256)
void lss_zero(float4* __restrict__ p, int n4)
{
    const int stride = gridDim.x * 256;
    for (int i = blockIdx.x * 256 + threadIdx.x; i < n4; i += stride)
        p[i] = make_float4(0.f, 0.f, 0.f, 0.f);
}

// One block (256 thr, 4 waves) per (b,n,w) column; wave wv handles h=4wv..4wv+3.
// Dedup voxels in an LDS hash table (per-lane slot cache skips repeat probes),
// then ONE 64-lane contiguous atomic set per unique voxel into ws[vox][64c],
// flagging bmap[vox]=1 (plain byte store) for the gated transpose.
__global__ __launch_bounds__(256)
void lss_scatter_dedup(const float* __restrict__ xf,
                       const float* __restrict__ rots,
                       const float* __restrict__ trans,
                       const float* __restrict__ intr,
                       const float* __restrict__ prots,
                       const float* __restrict__ ptrans,
                       float* __restrict__ ws,
                       unsigned char* __restrict__ bmap)
{
    __shared__ float s_lg[FHh * FWw];        // logits [h][d] (row stride 44)
    __shared__ float s_feat[FHh * CC];       // feats  [h][c]
    __shared__ float s_coef[NSLOT * 17];     // per-slot per-h coefficient (pad 17)
    __shared__ int   s_keys[NSLOT];
    __shared__ short s_list[NSLOT];          // compacted occupied-slot list
    __shared__ int   s_nslot;
    __shared__ int2  s_ovf[NOVF];
    __shared__ float s_ovfw[NOVF];
    __shared__ int   s_ovfcnt;

    const int tid  = threadIdx.x;
    const int lane = tid & 63;
    const int wv   = tid >> 6;          // 0..3

    // XCD swizzle: 1056 = 8*132; each XCD gets a contiguous run of columns
    const int obid = blockIdx.x;
    const int bid  = (obid & 7) * (NCOL / 8) + (obid >> 3);
    const int w   = bid % FWw;
    const int rem = bid / FWw;
    const int n   = rem % NN;
    const int b   = rem / NN;
    const int cam = b*NN + n;
    const float* colbase = xf + (size_t)cam * NCH * FHh * FWw + w;

    if (tid < NSLOT) s_keys[tid] = -1;
    for (int i = tid; i < NSLOT*17; i += 256) s_coef[i] = 0.0f;
    if (tid == 0) { s_nslot = 0; s_ovfcnt = 0; }

    // ---- cooperative stage of the whole column: 1680 scalars ----
    for (int t = tid; t < NCH*FHh; t += 256) {
        int h  = t / NCH;
        int ch = t - h*NCH;
        float v = colbase[(size_t)ch * (FHh*FWw) + h * FWw];
        if (ch < DD) s_lg[h*FWw + ch] = v;
        else         s_feat[(h << 6) + (ch - DD)] = v;
    }

    // ---- per-camera transform (double precision, redundant per thread) ----
    double K9[9], P9[9], R9[9];
    #pragma unroll
    for (int i = 0; i < 9; ++i) {
        K9[i] = (double)intr [cam*9 + i];
        P9[i] = (double)prots[cam*9 + i];
        R9[i] = (double)rots [cam*9 + i];
    }
    double Kinv[9], Pinv[9];
    inv3x3d(K9, Kinv);
    inv3x3d(P9, Pinv);
    double M[9];
    #pragma unroll
    for (int i = 0; i < 3; ++i)
        #pragma unroll
        for (int j = 0; j < 3; ++j)
            M[i*3+j] = R9[i*3+0]*Kinv[0*3+j] + R9[i*3+1]*Kinv[1*3+j] + R9[i*3+2]*Kinv[2*3+j];
    const double tx  = (double)trans [cam*3+0], ty  = (double)trans [cam*3+1], tz  = (double)trans [cam*3+2];
    const double ptx = (double)ptrans[cam*3+0], pty = (double)ptrans[cam*3+1], ptz = (double)ptrans[cam*3+2];

    __syncthreads();

    // ---- softmax + geometry + hash insert; wave wv handles h = 4wv..4wv+3
    int      last_vox  = -1;     // per-lane (vox -> slot) cache across h
    unsigned last_slot = 0;
    for (int r = 0; r < 4; ++r) {
        const int h = (wv << 2) + r;
        float logit = (lane < DD) ? s_lg[h*FWw + lane] : -INFINITY;
        float mx = logit;
        #pragma unroll
        for (int off = 32; off; off >>= 1) mx = fmaxf(mx, __shfl_xor(mx, off));
        float ex = (lane < DD) ? expf(logit - mx) : 0.0f;
        float sm = ex;
        #pragma unroll
        for (int off = 32; off; off >>= 1) sm += __shfl_xor(sm, off);
        const float wgt = ex / sm;

        int vox = -1;
        if (lane < DD) {
            double dz = 4.0 + (double)lane;
            double xs = (double)w * (703.0/43.0);
            double ys = (double)h * 17.0;
            double px = xs - ptx, py = ys - pty, pz = dz - ptz;
            double qx = Pinv[0]*px + Pinv[1]*py + Pinv[2]*pz;
            double qy = Pinv[3]*px + Pinv[4]*py + Pinv[5]*pz;
            double qz = Pinv[6]*px + Pinv[7]*py + Pinv[8]*pz;
            qx *= qz; qy *= qz;
            double gx = M[0]*qx + M[1]*qy + M[2]*qz + tx;
            double gy = M[3]*qx + M[4]*qy + M[5]*qz + ty;
            double gz = M[6]*qx + M[7]*qy + M[8]*qz + tz;
            double fx = floor((gx + 50.0) / 0.5);
            double fy = floor((gy + 50.0) / 0.5);
            double fz = floor((gz + 10.0) / 20.0);
            if (fx >= 0.0 && fx < (double)NXg &&
                fy >= 0.0 && fy < (double)NYg &&
                fz >= 0.0 && fz < (double)NZg) {
                int ix = (int)fx, iy = (int)fy, iz = (int)fz;
                vox = ((b*NZg + iz)*NXg + ix)*NYg + iy;   // < 160000
            }
        }

        if (vox >= 0) {
            if (vox == last_vox) {
                atomicAdd(&s_coef[last_slot*17 + h], wgt);
            } else {
                unsigned slot = (((unsigned)vox * 2654435761u) >> 18) & (NSLOT-1);
                bool done = false;
                for (int probe = 0; probe < NSLOT; ++probe) {
                    int prev = atomicCAS(&s_keys[slot], -1, vox);
                    if (prev == -1) {
                        int k = atomicAdd(&s_nslot, 1);
                        s_list[k] = (short)slot;
                    }
                    if (prev == -1 || prev == vox) {
                        atomicAdd(&s_coef[slot*17 + h], wgt);
                        last_vox = vox; last_slot = slot;
                        done = true;
                        break;
                    }
                    slot = (slot + 1) & (NSLOT-1);
                }
                if (!done) {   // table full: spill (generic-correctness fallback)
                    int k = atomicAdd(&s_ovfcnt, 1);
                    s_ovf[k]  = make_int2(vox, h);
                    s_ovfw[k] = wgt;
                    last_vox = -1;
                }
            }
        }
    }

    __syncthreads();

    // ---- hoist this lane's 16 feature values into registers ----
    float freg[FHh];
    #pragma unroll
    for (int h = 0; h < FHh; ++h) freg[h] = s_feat[(h << 6) + lane];

    // ---- emit: one 64-lane contiguous atomic set per unique voxel ----
    const int nocc = s_nslot;
    for (int e = wv; e < nocc; e += 4) {
        int slot = s_list[e];
        int vox  = s_keys[slot];
        float acc = 0.0f;
        #pragma unroll
        for (int h = 0; h < FHh; ++h)
            acc += s_coef[slot*17 + h] * freg[h];
        atomicAdd(&ws[(size_t)vox * CC + lane], acc);
        if (lane == 0) bmap[vox] = 1;    // idempotent flag for gated transpose
    }
    // ---- overflow entries (rare, generic fallback) ----
    const int novf = s_ovfcnt;
    for (int e = wv; e < novf; e += 4) {
        int vox = s_ovf[e].x, h = s_ovf[e].y;
        atomicAdd(&ws[(size_t)vox * CC + lane], s_ovfw[e] * freg[h]);
        if (lane == 0) bmap[vox] = 1;
    }
}

// ws [bz][40000 xy][64 c] -> out [bz][64 c][40000 xy]; bmap-gated tile reads.
__global__ __launch_bounds__(256)
void lss_transpose_g(const float* __restrict__ ws,
                     const unsigned char* __restrict__ bmap,
                     float* __restrict__ out)
{
    __shared__ float tile[CC][65];          // [c][xy], pad 65
    const int blk  = blockIdx.x;            // 4*625 = 2500 blocks
    const int bz   = blk / 625;
    const int xy0  = (blk % 625) * 64;
    const int t    = threadIdx.x;
    const int lane = t & 63;
    const int wv   = t >> 6;                // 0..3

    const int vb = bz * XYg + xy0;          // 64-aligned voxel base
    // one cache line of bmap decides the whole tile (block-uniform)
    const uint4* bm4 = (const uint4*)(bmap + vb);
    unsigned r = 0;
    #pragma unroll
    for (int i = 0; i < 4; ++i) {
        uint4 v = bm4[i];
        r |= v.x | v.y | v.z | v.w;
    }

    float* dst = out + (size_t)bz * CC * XYg + xy0;
    if (r == 0u) {
        const float4 z = make_float4(0.f, 0.f, 0.f, 0.f);
        #pragma unroll
        for (int rep = 0; rep < 4; ++rep) {
            int c = (wv << 4) + (rep << 2) + (lane >> 4);
            int q = lane & 15;
            ((float4*)(dst + (size_t)c * XYg))[q] = z;
        }
        return;
    }

    const float4* src = (const float4*)(ws + (size_t)vb * CC);
    #pragma unroll
    for (int rep = 0; rep < 4; ++rep) {
        int idx = (wv << 8) + (rep << 6) + lane;   // 64 consecutive float4/wave
        int xyl = idx >> 4;                        // 0..63
        int c4  = idx & 15;                        // float4 group within c
        float4 v = src[idx];
        tile[(c4<<2)+0][xyl] = v.x;
        tile[(c4<<2)+1][xyl] = v.y;
        tile[(c4<<2)+2][xyl] = v.z;
        tile[(c4<<2)+3][xyl] = v.w;
    }
    __syncthreads();
    #pragma unroll
    for (int rep = 0; rep < 4; ++rep) {
        int c   = (wv << 4) + (rep << 2) + (lane >> 4);  // 0..63
        int xy4 = lane & 15;                             // float4 within row
        float4 v = make_float4(tile[c][(xy4<<2)+0], tile[c][(xy4<<2)+1],
                               tile[c][(xy4<<2)+2], tile[c][(xy4<<2)+3]);
        ((float4*)(dst + (size_t)c * XYg))[xy4] = v;
    }
}

// ---------------- fallback (tiny ws): zero out + direct atomics -------------
__global__ __launch_bounds__(256)
void lss_scatter_direct(const float* __restrict__ xf,
                        const float* __restrict__ rots,
                        const float* __restrict__ trans,
                        const float* __restrict__ intr,
                        const float* __restrict__ prots,
                        const float* __restrict__ ptrans,
                        float* __restrict__ acc)
{
    const int wid  = blockIdx.x * 4 + (threadIdx.x >> 6);
    const int lane = threadIdx.x & 63;
    if (wid >= NPIX) return;
    int w  = wid % FWw;
    int t1 = wid / FWw;
    int h  = t1 % FHh; t1 /= FHh;
    int n  = t1 % NN;
    int b  = t1 / NN;
    const int cam = b*NN + n;

    double K9[9], P9[9], R9[9];
    #pragma unroll
    for (int i = 0; i < 9; ++i) {
        K9[i] = (double)intr [cam*9 + i];
        P9[i] = (double)prots[cam*9 + i];
        R9[i] = (double)rots [cam*9 + i];
    }
    double Kinv[9], Pinv[9];
    inv3x3d(K9, Kinv);
    inv3x3d(P9, Pinv);
    double M[9];
    #pragma unroll
    for (int i = 0; i < 3; ++i)
        #pragma unroll
        for (int j = 0; j < 3; ++j)
            M[i*3+j] = R9[i*3+0]*Kinv[0*3+j] + R9[i*3+1]*Kinv[1*3+j] + R9[i*3+2]*Kinv[2*3+j];
    const double tx  = (double)trans [cam*3+0], ty  = (double)trans [cam*3+1], tz  = (double)trans [cam*3+2];
    const double ptx = (double)ptrans[cam*3+0], pty = (double)ptrans[cam*3+1], ptz = (double)ptrans[cam*3+2];

    const size_t pixoff = (size_t)cam * NCH * FHh * FWw + (size_t)h * FWw + w;
    float logit = (lane < DD) ? xf[pixoff + (size_t)lane * (FHh*FWw)] : -INFINITY;
    float mx = logit;
    #pragma unroll
    for (int off = 32; off; off >>= 1) mx = fmaxf(mx, __shfl_xor(mx, off));
    float ex = (lane < DD) ? expf(logit - mx) : 0.0f;
    float sm = ex;
    #pragma unroll
    for (int off = 32; off; off >>= 1) sm += __shfl_xor(sm, off);
    const float wgt = ex / sm;

    int baddr = -1;
    if (lane < DD) {
        double dz = 4.0 + (double)lane;
        double xs = (double)w * (703.0/43.0);
        double ys = (double)h * 17.0;
        double px = xs - ptx, py = ys - pty, pz = dz - ptz;
        double qx = Pinv[0]*px + Pinv[1]*py + Pinv[2]*pz;
        double qy = Pinv[3]*px + Pinv[4]*py + Pinv[5]*pz;
        double qz = Pinv[6]*px + Pinv[7]*py + Pinv[8]*pz;
        qx *= qz; qy *= qz;
        double gx = M[0]*qx + M[1]*qy + M[2]*qz + tx;
        double gy = M[3]*qx + M[4]*qy + M[5]*qz + ty;
        double gz = M[6]*qx + M[7]*qy + M[8]*qz + tz;
        double fx = floor((gx + 50.0) / 0.5);
        double fy = floor((gy + 50.0) / 0.5);
        double fz = floor((gz + 10.0) / 20.0);
        if (fx >= 0.0 && fx < (double)NXg &&
            fy >= 0.0 && fy < (double)NYg &&
            fz >= 0.0 && fz < (double)NZg) {
            int ix = (int)fx, iy = (int)fy, iz = (int)fz;
            int bz = b*NZg + iz;
            baddr = bz * (CC*XYg) + ix*NYg + iy;
        }
    }

    const float f = xf[pixoff + (size_t)(DD + lane) * (FHh*FWw)];
    for (int d = 0; d < DD; ++d) {
        int   a  = __shfl(baddr, d);
        float wd = __shfl(wgt,   d);
        if (a >= 0) atomicAdd(&acc[(size_t)a + (size_t)lane * XYg], wd * f);
    }
}

extern "C" void kernel_launch(void* const* d_in, const int* in_sizes, int n_in,
                              void* d_out, int out_size, void* d_ws, size_t ws_size,
                              hipStream_t stream) {
    const float* xf     = (const float*)d_in[0];
    const float* rots   = (const float*)d_in[1];
    const float* trans  = (const float*)d_in[2];
    const float* intr   = (const float*)d_in[3];
    const float* prots  = (const float*)d_in[4];
    const float* ptrans = (const float*)d_in[5];
    float* out = (float*)d_out;

    if (ws_size >= (size_t)WS_NEED) {
        char* wsb = (char*)d_ws;
        float* ws = (float*)wsb;
        unsigned char* bmap = (unsigned char*)(wsb + BMAP_OFF);
        lss_zero<<<dim3(2048), dim3(256), 0, stream>>>(
            (float4*)wsb, ZERO_BYTES/16);
        lss_scatter_dedup<<<dim3(NCOL), dim3(256), 0, stream>>>(
            xf, rots, trans, intr, prots, ptrans, ws, bmap);
        lss_transpose_g<<<dim3(BB*NZg*625), dim3(256), 0, stream>>>(
            ws, bmap, out);
    } else {
        lss_zero<<<dim3(2048), dim3(256), 0, stream>>>(
            (float4*)out, (BB*NZg*XYg*CC)/4);
        lss_scatter_direct<<<dim3((NPIX + 3) / 4), dim3(256), 0, stream>>>(
            xf, rots, trans, intr, prots, ptrans, out);
    }
}

// Round 15
// 44.625 us; speedup vs baseline: 1.8326x; 1.0360x over previous
//
#include <hip/hip_runtime.h>
#include <math.h>

#define BB 4
#define NN 6
#define DD 41
#define CC 64
#define FHh 16
#define FWw 44
#define NXg 200
#define NYg 200
#define NZg 1
#define NSLOT 128
#define NOVF  (FHh*DD)                 // 656 worst-case points per column
#define XYg (NXg*NYg)                  // 40000
#define NVOX (BB*NZg*NXg*NYg)          // 160000
#define NCOL (BB*NN*FWw)               // 1056 columns
#define NPIX (BB*NN*FHh*FWw)           // 16896
#define NCH  (DD+CC)                   // 105
#define NTILE (NVOX/64)                // 2500

// ws layout: wsv[NVOX][CC] floats, then per-TILE byte map bmapT[NTILE]
#define WSV_BYTES  (NVOX*CC*4u)        // 40,960,000
#define BMAP_OFF   WSV_BYTES
#define ZERO_BYTES (WSV_BYTES + 2560u) // wsv + tile map (16B multiple)
#define WS_NEED    ZERO_BYTES

__device__ __forceinline__ void inv3x3d(const double m[9], double o[9]) {
    double a=m[0],b=m[1],c=m[2],d=m[3],e=m[4],f=m[5],g=m[6],h=m[7],i=m[8];
    double A = e*i - f*h;
    double Bv = -(d*i - f*g);
    double Cv = d*h - e*g;
    double det = a*A + b*Bv + c*Cv;
    double r = 1.0/det;
    o[0]=A*r;  o[1]=-(b*i-c*h)*r; o[2]=(b*f-c*e)*r;
    o[3]=Bv*r; o[4]=(a*i-c*g)*r;  o[5]=-(a*f-c*d)*r;
    o[6]=Cv*r; o[7]=-(a*h-b*g)*r; o[8]=(a*e-b*d)*r;
}

// fast zero-fill: grid-stride float4 (covers wsv + tile map)
__global__ __launch_bounds__(256)
void lss_zero(float4* __restrict__ p, int n4)
{
    const int stride = gridDim.x * 256;
    for (int i = blockIdx.x * 256 + threadIdx.x; i < n4; i += stride)
        p[i] = make_float4(0.f, 0.f, 0.f, 0.f);
}

// One block (256 thr, 4 waves) per (b,n,w) column; wave wv handles h=4wv..4wv+3.
// Logits are loaded straight from global (prefetched, no LDS round-trip);
// only the reused feature slice is staged. Dedup voxels in an LDS hash table,
// then ONE 64-lane contiguous atomic set per unique voxel into ws[vox][64c],
// flagging bmapT[vox>>6]=1 (plain byte store) for the gated transpose.
__global__ __launch_bounds__(256)
void lss_scatter_dedup(const float* __restrict__ xf,
                       const float* __restrict__ rots,
                       const float* __restrict__ trans,
                       const float* __restrict__ intr,
                       const float* __restrict__ prots,
                       const float* __restrict__ ptrans,
                       float* __restrict__ ws,
                       unsigned char* __restrict__ bmapT)
{
    __shared__ float s_feat[FHh * CC];       // feats  [h][c]
    __shared__ float s_coef[NSLOT * 17];     // per-slot per-h coefficient (pad 17)
    __shared__ int   s_keys[NSLOT];
    __shared__ short s_list[NSLOT];          // compacted occupied-slot list
    __shared__ int   s_nslot;
    __shared__ int2  s_ovf[NOVF];
    __shared__ float s_ovfw[NOVF];
    __shared__ int   s_ovfcnt;

    const int tid  = threadIdx.x;
    const int lane = tid & 63;
    const int wv   = tid >> 6;          // 0..3

    // XCD swizzle: 1056 = 8*132; each XCD gets a contiguous run of columns
    const int obid = blockIdx.x;
    const int bid  = (obid & 7) * (NCOL / 8) + (obid >> 3);
    const int w   = bid % FWw;
    const int rem = bid / FWw;
    const int n   = rem % NN;
    const int b   = rem / NN;
    const int cam = b*NN + n;
    const float* colbase = xf + (size_t)cam * NCH * FHh * FWw + w;

    // ---- prefetch this lane's 4 logits (independent, in flight early) ----
    float lgt[4];
    #pragma unroll
    for (int r = 0; r < 4; ++r) {
        const int h = (wv << 2) + r;
        lgt[r] = (lane < DD)
            ? colbase[(size_t)lane * (FHh*FWw) + h * FWw] : -INFINITY;
    }

    if (tid < NSLOT) s_keys[tid] = -1;
    for (int i = tid; i < NSLOT*17; i += 256) s_coef[i] = 0.0f;
    if (tid == 0) { s_nslot = 0; s_ovfcnt = 0; }

    // ---- stage only the reused features: 1024 scalars ----
    for (int t = tid; t < FHh*CC; t += 256) {
        int h = t >> 6, c = t & 63;
        s_feat[t] = colbase[(size_t)(DD + c) * (FHh*FWw) + h * FWw];
    }

    // ---- per-camera transform (double precision, redundant per thread) ----
    double K9[9], P9[9], R9[9];
    #pragma unroll
    for (int i = 0; i < 9; ++i) {
        K9[i] = (double)intr [cam*9 + i];
        P9[i] = (double)prots[cam*9 + i];
        R9[i] = (double)rots [cam*9 + i];
    }
    double Kinv[9], Pinv[9];
    inv3x3d(K9, Kinv);
    inv3x3d(P9, Pinv);
    double M[9];
    #pragma unroll
    for (int i = 0; i < 3; ++i)
        #pragma unroll
        for (int j = 0; j < 3; ++j)
            M[i*3+j] = R9[i*3+0]*Kinv[0*3+j] + R9[i*3+1]*Kinv[1*3+j] + R9[i*3+2]*Kinv[2*3+j];
    const double tx  = (double)trans [cam*3+0], ty  = (double)trans [cam*3+1], tz  = (double)trans [cam*3+2];
    const double ptx = (double)ptrans[cam*3+0], pty = (double)ptrans[cam*3+1], ptz = (double)ptrans[cam*3+2];

    __syncthreads();   // s_keys/s_coef init + s_feat visible

    // ---- softmax + geometry + hash insert; wave wv handles h = 4wv..4wv+3
    int      last_vox  = -1;     // per-lane (vox -> slot) cache across h
    unsigned last_slot = 0;
    for (int r = 0; r < 4; ++r) {
        const int h = (wv << 2) + r;
        float logit = lgt[r];
        float mx = logit;
        #pragma unroll
        for (int off = 32; off; off >>= 1) mx = fmaxf(mx, __shfl_xor(mx, off));
        float ex = (lane < DD) ? expf(logit - mx) : 0.0f;
        float sm = ex;
        #pragma unroll
        for (int off = 32; off; off >>= 1) sm += __shfl_xor(sm, off);
        const float wgt = ex / sm;

        int vox = -1;
        if (lane < DD) {
            double dz = 4.0 + (double)lane;
            double xs = (double)w * (703.0/43.0);
            double ys = (double)h * 17.0;
            double px = xs - ptx, py = ys - pty, pz = dz - ptz;
            double qx = Pinv[0]*px + Pinv[1]*py + Pinv[2]*pz;
            double qy = Pinv[3]*px + Pinv[4]*py + Pinv[5]*pz;
            double qz = Pinv[6]*px + Pinv[7]*py + Pinv[8]*pz;
            qx *= qz; qy *= qz;
            double gx = M[0]*qx + M[1]*qy + M[2]*qz + tx;
            double gy = M[3]*qx + M[4]*qy + M[5]*qz + ty;
            double gz = M[6]*qx + M[7]*qy + M[8]*qz + tz;
            double fx = floor((gx + 50.0) / 0.5);
            double fy = floor((gy + 50.0) / 0.5);
            double fz = floor((gz + 10.0) / 20.0);
            if (fx >= 0.0 && fx < (double)NXg &&
                fy >= 0.0 && fy < (double)NYg &&
                fz >= 0.0 && fz < (double)NZg) {
                int ix = (int)fx, iy = (int)fy, iz = (int)fz;
                vox = ((b*NZg + iz)*NXg + ix)*NYg + iy;   // < 160000
            }
        }

        if (vox >= 0) {
            if (vox == last_vox) {
                atomicAdd(&s_coef[last_slot*17 + h], wgt);
            } else {
                unsigned slot = (((unsigned)vox * 2654435761u) >> 18) & (NSLOT-1);
                bool done = false;
                for (int probe = 0; probe < NSLOT; ++probe) {
                    int prev = atomicCAS(&s_keys[slot], -1, vox);
                    if (prev == -1) {
                        int k = atomicAdd(&s_nslot, 1);
                        s_list[k] = (short)slot;
                    }
                    if (prev == -1 || prev == vox) {
                        atomicAdd(&s_coef[slot*17 + h], wgt);
                        last_vox = vox; last_slot = slot;
                        done = true;
                        break;
                    }
                    slot = (slot + 1) & (NSLOT-1);
                }
                if (!done) {   // table full: spill (generic-correctness fallback)
                    int k = atomicAdd(&s_ovfcnt, 1);
                    s_ovf[k]  = make_int2(vox, h);
                    s_ovfw[k] = wgt;
                    last_vox = -1;
                }
            }
        }
    }

    __syncthreads();

    // ---- hoist this lane's 16 feature values into registers ----
    float freg[FHh];
    #pragma unroll
    for (int h = 0; h < FHh; ++h) freg[h] = s_feat[(h << 6) + lane];

    // ---- emit: one 64-lane contiguous atomic set per unique voxel ----
    const int nocc = s_nslot;
    for (int e = wv; e < nocc; e += 4) {
        int slot = s_list[e];
        int vox  = s_keys[slot];
        float acc = 0.0f;
        #pragma unroll
        for (int h = 0; h < FHh; ++h)
            acc += s_coef[slot*17 + h] * freg[h];
        atomicAdd(&ws[(size_t)vox * CC + lane], acc);
        if (lane == 0) bmapT[vox >> 6] = 1;   // tile-level flag (idempotent)
    }
    // ---- overflow entries (rare, generic fallback) ----
    const int novf = s_ovfcnt;
    for (int e = wv; e < novf; e += 4) {
        int vox = s_ovf[e].x, h = s_ovf[e].y;
        atomicAdd(&ws[(size_t)vox * CC + lane], s_ovfw[e] * freg[h]);
        if (lane == 0) bmapT[vox >> 6] = 1;
    }
}

// ws [bz][40000 xy][64 c] -> out [bz][64 c][40000 xy]; tile-byte-gated reads.
__global__ __launch_bounds__(256)
void lss_transpose_g(const float* __restrict__ ws,
                     const unsigned char* __restrict__ bmapT,
                     float* __restrict__ out)
{
    __shared__ float tile[CC][65];          // [c][xy], pad 65
    const int blk  = blockIdx.x;            // 2500 blocks; tile id == blk
    const int bz   = blk / 625;
    const int xy0  = (blk % 625) * 64;
    const int t    = threadIdx.x;
    const int lane = t & 63;
    const int wv   = t >> 6;                // 0..3

    float* dst = out + (size_t)bz * CC * XYg + xy0;
    if (bmapT[blk] == 0) {                  // one broadcast byte decides tile
        const float4 z = make_float4(0.f, 0.f, 0.f, 0.f);
        #pragma unroll
        for (int rep = 0; rep < 4; ++rep) {
            int c = (wv << 4) + (rep << 2) + (lane >> 4);
            int q = lane & 15;
            ((float4*)(dst + (size_t)c * XYg))[q] = z;
        }
        return;
    }

    const int vb = bz * XYg + xy0;          // 64-aligned voxel base
    const float4* src = (const float4*)(ws + (size_t)vb * CC);
    #pragma unroll
    for (int rep = 0; rep < 4; ++rep) {
        int idx = (wv << 8) + (rep << 6) + lane;   // 64 consecutive float4/wave
        int xyl = idx >> 4;                        // 0..63
        int c4  = idx & 15;                        // float4 group within c
        float4 v = src[idx];
        tile[(c4<<2)+0][xyl] = v.x;
        tile[(c4<<2)+1][xyl] = v.y;
        tile[(c4<<2)+2][xyl] = v.z;
        tile[(c4<<2)+3][xyl] = v.w;
    }
    __syncthreads();
    #pragma unroll
    for (int rep = 0; rep < 4; ++rep) {
        int c   = (wv << 4) + (rep << 2) + (lane >> 4);  // 0..63
        int xy4 = lane & 15;                             // float4 within row
        float4 v = make_float4(tile[c][(xy4<<2)+0], tile[c][(xy4<<2)+1],
                               tile[c][(xy4<<2)+2], tile[c][(xy4<<2)+3]);
        ((float4*)(dst + (size_t)c * XYg))[xy4] = v;
    }
}

// ---------------- fallback (tiny ws): zero out + direct atomics -------------
__global__ __launch_bounds__(256)
void lss_scatter_direct(const float* __restrict__ xf,
                        const float* __restrict__ rots,
                        const float* __restrict__ trans,
                        const float* __restrict__ intr,
                        const float* __restrict__ prots,
                        const float* __restrict__ ptrans,
                        float* __restrict__ acc)
{
    const int wid  = blockIdx.x * 4 + (threadIdx.x >> 6);
    const int lane = threadIdx.x & 63;
    if (wid >= NPIX) return;
    int w  = wid % FWw;
    int t1 = wid / FWw;
    int h  = t1 % FHh; t1 /= FHh;
    int n  = t1 % NN;
    int b  = t1 / NN;
    const int cam = b*NN + n;

    double K9[9], P9[9], R9[9];
    #pragma unroll
    for (int i = 0; i < 9; ++i) {
        K9[i] = (double)intr [cam*9 + i];
        P9[i] = (double)prots[cam*9 + i];
        R9[i] = (double)rots [cam*9 + i];
    }
    double Kinv[9], Pinv[9];
    inv3x3d(K9, Kinv);
    inv3x3d(P9, Pinv);
    double M[9];
    #pragma unroll
    for (int i = 0; i < 3; ++i)
        #pragma unroll
        for (int j = 0; j < 3; ++j)
            M[i*3+j] = R9[i*3+0]*Kinv[0*3+j] + R9[i*3+1]*Kinv[1*3+j] + R9[i*3+2]*Kinv[2*3+j];
    const double tx  = (double)trans [cam*3+0], ty  = (double)trans [cam*3+1], tz  = (double)trans [cam*3+2];
    const double ptx = (double)ptrans[cam*3+0], pty = (double)ptrans[cam*3+1], ptz = (double)ptrans[cam*3+2];

    const size_t pixoff = (size_t)cam * NCH * FHh * FWw + (size_t)h * FWw + w;
    float logit = (lane < DD) ? xf[pixoff + (size_t)lane * (FHh*FWw)] : -INFINITY;
    float mx = logit;
    #pragma unroll
    for (int off = 32; off; off >>= 1) mx = fmaxf(mx, __shfl_xor(mx, off));
    float ex = (lane < DD) ? expf(logit - mx) : 0.0f;
    float sm = ex;
    #pragma unroll
    for (int off = 32; off; off >>= 1) sm += __shfl_xor(sm, off);
    const float wgt = ex / sm;

    int baddr = -1;
    if (lane < DD) {
        double dz = 4.0 + (double)lane;
        double xs = (double)w * (703.0/43.0);
        double ys = (double)h * 17.0;
        double px = xs - ptx, py = ys - pty, pz = dz - ptz;
        double qx = Pinv[0]*px + Pinv[1]*py + Pinv[2]*pz;
        double qy = Pinv[3]*px + Pinv[4]*py + Pinv[5]*pz;
        double qz = Pinv[6]*px + Pinv[7]*py + Pinv[8]*pz;
        qx *= qz; qy *= qz;
        double gx = M[0]*qx + M[1]*qy + M[2]*qz + tx;
        double gy = M[3]*qx + M[4]*qy + M[5]*qz + ty;
        double gz = M[6]*qx + M[7]*qy + M[8]*qz + tz;
        double fx = floor((gx + 50.0) / 0.5);
        double fy = floor((gy + 50.0) / 0.5);
        double fz = floor((gz + 10.0) / 20.0);
        if (fx >= 0.0 && fx < (double)NXg &&
            fy >= 0.0 && fy < (double)NYg &&
            fz >= 0.0 && fz < (double)NZg) {
            int ix = (int)fx, iy = (int)fy, iz = (int)fz;
            int bz = b*NZg + iz;
            baddr = bz * (CC*XYg) + ix*NYg + iy;
        }
    }

    const float f = xf[pixoff + (size_t)(DD + lane) * (FHh*FWw)];
    for (int d = 0; d < DD; ++d) {
        int   a  = __shfl(baddr, d);
        float wd = __shfl(wgt,   d);
        if (a >= 0) atomicAdd(&acc[(size_t)a + (size_t)lane * XYg], wd * f);
    }
}

extern "C" void kernel_launch(void* const* d_in, const int* in_sizes, int n_in,
                              void* d_out, int out_size, void* d_ws, size_t ws_size,
                              hipStream_t stream) {
    const float* xf     = (const float*)d_in[0];
    const float* rots   = (const float*)d_in[1];
    const float* trans  = (const float*)d_in[2];
    const float* intr   = (const float*)d_in[3];
    const float* prots  = (const float*)d_in[4];
    const float* ptrans = (const float*)d_in[5];
    float* out = (float*)d_out;

    if (ws_size >= (size_t)WS_NEED) {
        char* wsb = (char*)d_ws;
        float* ws = (float*)wsb;
        unsigned char* bmapT = (unsigned char*)(wsb + BMAP_OFF);
        lss_zero<<<dim3(2048), dim3(256), 0, stream>>>(
            (float4*)wsb, ZERO_BYTES/16);
        lss_scatter_dedup<<<dim3(NCOL), dim3(256), 0, stream>>>(
            xf, rots, trans, intr, prots, ptrans, ws, bmapT);
        lss_transpose_g<<<dim3(NTILE), dim3(256), 0, stream>>>(
            ws, bmapT, out);
    } else {
        lss_zero<<<dim3(2048), dim3(256), 0, stream>>>(
            (float4*)out, (BB*NZg*XYg*CC)/4);
        lss_scatter_direct<<<dim3((NPIX + 3) / 4), dim3(256), 0, stream>>>(
            xf, rots, trans, intr, prots, ptrans, out);
    }
}

// Round 16
// 44.457 us; speedup vs baseline: 1.8396x; 1.0038x over previous
//
#include <hip/hip_runtime.h>
#include <hip/hip_cooperative_groups.h>
#include <math.h>

namespace cg = cooperative_groups;

#define BB 4
#define NN 6
#define DD 41
#define CC 64
#define FHh 16
#define FWw 44
#define NXg 200
#define NYg 200
#define NZg 1
#define NSLOT 128
#define NOVF  (FHh*DD)                 // 656 worst-case points per column
#define XYg (NXg*NYg)                  // 40000
#define NVOX (BB*NZg*NXg*NYg)          // 160000
#define NCOL (BB*NN*FWw)               // 1056 columns
#define NPIX (BB*NN*FHh*FWw)           // 16896
#define NCH  (DD+CC)                   // 105
#define NTILE (NVOX/64)                // 2500

// ws layout
#define WSV_OFF   0u
#define BMAPV_OFF 40960000u            // per-voxel byte map, 160000 B
#define BMAPT_OFF 41120000u            // per-tile byte map (fallback path), 2500 B
#define WS_NEED   41122560u

__device__ __forceinline__ void inv3x3d(const double m[9], double o[9]) {
    double a=m[0],b=m[1],c=m[2],d=m[3],e=m[4],f=m[5],g=m[6],h=m[7],i=m[8];
    double A = e*i - f*h;
    double Bv = -(d*i - f*g);
    double Cv = d*h - e*g;
    double det = a*A + b*Bv + c*Cv;
    double r = 1.0/det;
    o[0]=A*r;  o[1]=-(b*i-c*h)*r; o[2]=(b*f-c*e)*r;
    o[3]=Bv*r; o[4]=(a*i-c*g)*r;  o[5]=-(a*f-c*d)*r;
    o[6]=Cv*r; o[7]=-(a*h-b*g)*r; o[8]=(a*e-b*d)*r;
}

__global__ __launch_bounds__(256)
void lss_zero(float4* __restrict__ p, int n4)
{
    const int stride = gridDim.x * 256;
    for (int i = blockIdx.x * 256 + threadIdx.x; i < n4; i += stride)
        p[i] = make_float4(0.f, 0.f, 0.f, 0.f);
}

// =================== fused cooperative kernel (primary path) ================
// P1 front -> P2 zero-own-rows + bmap flags -> grid.sync -> P3 emit atomics
// -> grid.sync -> P4 per-row-gated transpose. LDS: ovf arrays alias the
// transpose tile (phase-disjoint). 30.2 KB LDS, min 5 blocks/CU.
__global__ __launch_bounds__(256, 5)
void lss_fused(const float* __restrict__ xf,
               const float* __restrict__ rots,
               const float* __restrict__ trans,
               const float* __restrict__ intr,
               const float* __restrict__ prots,
               const float* __restrict__ ptrans,
               float* __restrict__ ws,
               unsigned char* __restrict__ bmap,
               float* __restrict__ out)
{
    cg::grid_group grid = cg::this_grid();

    __shared__ float s_feat[FHh * CC];              // 4 KB
    __shared__ float s_coef[NSLOT * 17];            // 8.5 KB
    __shared__ int   s_keys[NSLOT];
    __shared__ short s_list[NSLOT];
    __shared__ int   s_nslot;
    __shared__ int   s_ovfcnt;
    __shared__ __align__(16) float s_tile[CC * 65]; // 16.6 KB; P1-P3: ovf alias
    int2*  s_ovf  = (int2*)s_tile;                  // 656 int2 = 1312 floats
    float* s_ovfw = s_tile + 1312;                  // 656 floats

    const int tid  = threadIdx.x;
    const int lane = tid & 63;
    const int wv   = tid >> 6;          // 0..3

    // XCD swizzle: 1056 = 8*132
    const int obid = blockIdx.x;
    const int bid  = (obid & 7) * (NCOL / 8) + (obid >> 3);
    const int w   = bid % FWw;
    const int rem = bid / FWw;
    const int n   = rem % NN;
    const int b   = rem / NN;
    const int cam = b*NN + n;
    const float* colbase = xf + (size_t)cam * NCH * FHh * FWw + w;

    // ---- P1: prefetch logits, stage feats, f64 geometry, hash dedup ----
    float lgt[4];
    #pragma unroll
    for (int r = 0; r < 4; ++r) {
        const int h = (wv << 2) + r;
        lgt[r] = (lane < DD)
            ? colbase[(size_t)lane * (FHh*FWw) + h * FWw] : -INFINITY;
    }

    if (tid < NSLOT) s_keys[tid] = -1;
    for (int i = tid; i < NSLOT*17; i += 256) s_coef[i] = 0.0f;
    if (tid == 0) { s_nslot = 0; s_ovfcnt = 0; }

    for (int t = tid; t < FHh*CC; t += 256) {
        int h = t >> 6, c = t & 63;
        s_feat[t] = colbase[(size_t)(DD + c) * (FHh*FWw) + h * FWw];
    }

    double K9[9], P9[9], R9[9];
    #pragma unroll
    for (int i = 0; i < 9; ++i) {
        K9[i] = (double)intr [cam*9 + i];
        P9[i] = (double)prots[cam*9 + i];
        R9[i] = (double)rots [cam*9 + i];
    }
    double Kinv[9], Pinv[9];
    inv3x3d(K9, Kinv);
    inv3x3d(P9, Pinv);
    double M[9];
    #pragma unroll
    for (int i = 0; i < 3; ++i)
        #pragma unroll
        for (int j = 0; j < 3; ++j)
            M[i*3+j] = R9[i*3+0]*Kinv[0*3+j] + R9[i*3+1]*Kinv[1*3+j] + R9[i*3+2]*Kinv[2*3+j];
    const double tx  = (double)trans [cam*3+0], ty  = (double)trans [cam*3+1], tz  = (double)trans [cam*3+2];
    const double ptx = (double)ptrans[cam*3+0], pty = (double)ptrans[cam*3+1], ptz = (double)ptrans[cam*3+2];

    __syncthreads();

    int      last_vox  = -1;
    unsigned last_slot = 0;
    for (int r = 0; r < 4; ++r) {
        const int h = (wv << 2) + r;
        float logit = lgt[r];
        float mx = logit;
        #pragma unroll
        for (int off = 32; off; off >>= 1) mx = fmaxf(mx, __shfl_xor(mx, off));
        float ex = (lane < DD) ? expf(logit - mx) : 0.0f;
        float sm = ex;
        #pragma unroll
        for (int off = 32; off; off >>= 1) sm += __shfl_xor(sm, off);
        const float wgt = ex / sm;

        int vox = -1;
        if (lane < DD) {
            double dz = 4.0 + (double)lane;
            double xs = (double)w * (703.0/43.0);
            double ys = (double)h * 17.0;
            double px = xs - ptx, py = ys - pty, pz = dz - ptz;
            double qx = Pinv[0]*px + Pinv[1]*py + Pinv[2]*pz;
            double qy = Pinv[3]*px + Pinv[4]*py + Pinv[5]*pz;
            double qz = Pinv[6]*px + Pinv[7]*py + Pinv[8]*pz;
            qx *= qz; qy *= qz;
            double gx = M[0]*qx + M[1]*qy + M[2]*qz + tx;
            double gy = M[3]*qx + M[4]*qy + M[5]*qz + ty;
            double gz = M[6]*qx + M[7]*qy + M[8]*qz + tz;
            double fx = floor((gx + 50.0) / 0.5);
            double fy = floor((gy + 50.0) / 0.5);
            double fz = floor((gz + 10.0) / 20.0);
            if (fx >= 0.0 && fx < (double)NXg &&
                fy >= 0.0 && fy < (double)NYg &&
                fz >= 0.0 && fz < (double)NZg) {
                int ix = (int)fx, iy = (int)fy, iz = (int)fz;
                vox = ((b*NZg + iz)*NXg + ix)*NYg + iy;
            }
        }

        if (vox >= 0) {
            if (vox == last_vox) {
                atomicAdd(&s_coef[last_slot*17 + h], wgt);
            } else {
                unsigned slot = (((unsigned)vox * 2654435761u) >> 18) & (NSLOT-1);
                bool done = false;
                for (int probe = 0; probe < NSLOT; ++probe) {
                    int prev = atomicCAS(&s_keys[slot], -1, vox);
                    if (prev == -1) {
                        int k = atomicAdd(&s_nslot, 1);
                        s_list[k] = (short)slot;
                    }
                    if (prev == -1 || prev == vox) {
                        atomicAdd(&s_coef[slot*17 + h], wgt);
                        last_vox = vox; last_slot = slot;
                        done = true;
                        break;
                    }
                    slot = (slot + 1) & (NSLOT-1);
                }
                if (!done) {
                    int k = atomicAdd(&s_ovfcnt, 1);
                    s_ovf[k]  = make_int2(vox, h);
                    s_ovfw[k] = wgt;
                    last_vox = -1;
                }
            }
        }
    }

    __syncthreads();
    const int nocc = s_nslot;
    const int novf = s_ovfcnt;

    float freg[FHh];
    #pragma unroll
    for (int h = 0; h < FHh; ++h) freg[h] = s_feat[(h << 6) + lane];

    // ---- P2: zero own unique ws rows + set per-voxel byte flags ----
    for (int e = wv; e < nocc; e += 4) {
        int vox = s_keys[s_list[e]];
        ws[(size_t)vox * CC + lane] = 0.0f;
        if (lane == 0) bmap[vox] = 1;
    }
    for (int e = wv; e < novf; e += 4) {
        int vox = s_ovf[e].x;
        ws[(size_t)vox * CC + lane] = 0.0f;
        if (lane == 0) bmap[vox] = 1;
    }

    __threadfence();
    grid.sync();     // all row-zeros + flags visible everywhere

    // ---- P3: emit one 64-lane contiguous atomic row per unique voxel ----
    for (int e = wv; e < nocc; e += 4) {
        int slot = s_list[e];
        int vox  = s_keys[slot];
        float acc = 0.0f;
        #pragma unroll
        for (int h = 0; h < FHh; ++h)
            acc += s_coef[slot*17 + h] * freg[h];
        atomicAdd(&ws[(size_t)vox * CC + lane], acc);
    }
    for (int e = wv; e < novf; e += 4) {
        int vox = s_ovf[e].x, h = s_ovf[e].y;
        atomicAdd(&ws[(size_t)vox * CC + lane], s_ovfw[e] * freg[h]);
    }

    __threadfence();
    grid.sync();     // all adds done

    // ---- P4: per-row bmap-gated transpose (s_tile now free) ----
    const float4 z4 = make_float4(0.f, 0.f, 0.f, 0.f);
    for (int t = blockIdx.x; t < NTILE; t += NCOL) {
        const int bz  = t / 625;
        const int xy0 = (t % 625) * 64;
        const int vb  = bz * XYg + xy0;
        const float4* src = (const float4*)(ws + (size_t)vb * CC);
        #pragma unroll
        for (int rep = 0; rep < 4; ++rep) {
            int idx = (wv << 8) + (rep << 6) + lane;
            int xyl = idx >> 4;
            int c4  = idx & 15;
            float4 v = bmap[vb + xyl] ? src[idx] : z4;
            s_tile[((c4<<2)+0)*65 + xyl] = v.x;
            s_tile[((c4<<2)+1)*65 + xyl] = v.y;
            s_tile[((c4<<2)+2)*65 + xyl] = v.z;
            s_tile[((c4<<2)+3)*65 + xyl] = v.w;
        }
        __syncthreads();
        float* dst = out + (size_t)bz * CC * XYg + xy0;
        #pragma unroll
        for (int rep = 0; rep < 4; ++rep) {
            int c = (wv << 4) + (rep << 2) + (lane >> 4);
            int q = lane & 15;
            float4 v = make_float4(s_tile[c*65 + 4*q + 0], s_tile[c*65 + 4*q + 1],
                                   s_tile[c*65 + 4*q + 2], s_tile[c*65 + 4*q + 3]);
            ((float4*)(dst + (size_t)c * XYg))[q] = v;
        }
        __syncthreads();
    }
}

// ====================== R15 fallback path (proven, 44.6 µs) =================
__global__ __launch_bounds__(256)
void lss_scatter_dedup(const float* __restrict__ xf,
                       const float* __restrict__ rots,
                       const float* __restrict__ trans,
                       const float* __restrict__ intr,
                       const float* __restrict__ prots,
                       const float* __restrict__ ptrans,
                       float* __restrict__ ws,
                       unsigned char* __restrict__ bmapT)
{
    __shared__ float s_feat[FHh * CC];
    __shared__ float s_coef[NSLOT * 17];
    __shared__ int   s_keys[NSLOT];
    __shared__ short s_list[NSLOT];
    __shared__ int   s_nslot;
    __shared__ int2  s_ovf[NOVF];
    __shared__ float s_ovfw[NOVF];
    __shared__ int   s_ovfcnt;

    const int tid  = threadIdx.x;
    const int lane = tid & 63;
    const int wv   = tid >> 6;

    const int obid = blockIdx.x;
    const int bid  = (obid & 7) * (NCOL / 8) + (obid >> 3);
    const int w   = bid % FWw;
    const int rem = bid / FWw;
    const int n   = rem % NN;
    const int b   = rem / NN;
    const int cam = b*NN + n;
    const float* colbase = xf + (size_t)cam * NCH * FHh * FWw + w;

    float lgt[4];
    #pragma unroll
    for (int r = 0; r < 4; ++r) {
        const int h = (wv << 2) + r;
        lgt[r] = (lane < DD)
            ? colbase[(size_t)lane * (FHh*FWw) + h * FWw] : -INFINITY;
    }

    if (tid < NSLOT) s_keys[tid] = -1;
    for (int i = tid; i < NSLOT*17; i += 256) s_coef[i] = 0.0f;
    if (tid == 0) { s_nslot = 0; s_ovfcnt = 0; }

    for (int t = tid; t < FHh*CC; t += 256) {
        int h = t >> 6, c = t & 63;
        s_feat[t] = colbase[(size_t)(DD + c) * (FHh*FWw) + h * FWw];
    }

    double K9[9], P9[9], R9[9];
    #pragma unroll
    for (int i = 0; i < 9; ++i) {
        K9[i] = (double)intr [cam*9 + i];
        P9[i] = (double)prots[cam*9 + i];
        R9[i] = (double)rots [cam*9 + i];
    }
    double Kinv[9], Pinv[9];
    inv3x3d(K9, Kinv);
    inv3x3d(P9, Pinv);
    double M[9];
    #pragma unroll
    for (int i = 0; i < 3; ++i)
        #pragma unroll
        for (int j = 0; j < 3; ++j)
            M[i*3+j] = R9[i*3+0]*Kinv[0*3+j] + R9[i*3+1]*Kinv[1*3+j] + R9[i*3+2]*Kinv[2*3+j];
    const double tx  = (double)trans [cam*3+0], ty  = (double)trans [cam*3+1], tz  = (double)trans [cam*3+2];
    const double ptx = (double)ptrans[cam*3+0], pty = (double)ptrans[cam*3+1], ptz = (double)ptrans[cam*3+2];

    __syncthreads();

    int      last_vox  = -1;
    unsigned last_slot = 0;
    for (int r = 0; r < 4; ++r) {
        const int h = (wv << 2) + r;
        float logit = lgt[r];
        float mx = logit;
        #pragma unroll
        for (int off = 32; off; off >>= 1) mx = fmaxf(mx, __shfl_xor(mx, off));
        float ex = (lane < DD) ? expf(logit - mx) : 0.0f;
        float sm = ex;
        #pragma unroll
        for (int off = 32; off; off >>= 1) sm += __shfl_xor(sm, off);
        const float wgt = ex / sm;

        int vox = -1;
        if (lane < DD) {
            double dz = 4.0 + (double)lane;
            double xs = (double)w * (703.0/43.0);
            double ys = (double)h * 17.0;
            double px = xs - ptx, py = ys - pty, pz = dz - ptz;
            double qx = Pinv[0]*px + Pinv[1]*py + Pinv[2]*pz;
            double qy = Pinv[3]*px + Pinv[4]*py + Pinv[5]*pz;
            double qz = Pinv[6]*px + Pinv[7]*py + Pinv[8]*pz;
            qx *= qz; qy *= qz;
            double gx = M[0]*qx + M[1]*qy + M[2]*qz + tx;
            double gy = M[3]*qx + M[4]*qy + M[5]*qz + ty;
            double gz = M[6]*qx + M[7]*qy + M[8]*qz + tz;
            double fx = floor((gx + 50.0) / 0.5);
            double fy = floor((gy + 50.0) / 0.5);
            double fz = floor((gz + 10.0) / 20.0);
            if (fx >= 0.0 && fx < (double)NXg &&
                fy >= 0.0 && fy < (double)NYg &&
                fz >= 0.0 && fz < (double)NZg) {
                int ix = (int)fx, iy = (int)fy, iz = (int)fz;
                vox = ((b*NZg + iz)*NXg + ix)*NYg + iy;
            }
        }

        if (vox >= 0) {
            if (vox == last_vox) {
                atomicAdd(&s_coef[last_slot*17 + h], wgt);
            } else {
                unsigned slot = (((unsigned)vox * 2654435761u) >> 18) & (NSLOT-1);
                bool done = false;
                for (int probe = 0; probe < NSLOT; ++probe) {
                    int prev = atomicCAS(&s_keys[slot], -1, vox);
                    if (prev == -1) {
                        int k = atomicAdd(&s_nslot, 1);
                        s_list[k] = (short)slot;
                    }
                    if (prev == -1 || prev == vox) {
                        atomicAdd(&s_coef[slot*17 + h], wgt);
                        last_vox = vox; last_slot = slot;
                        done = true;
                        break;
                    }
                    slot = (slot + 1) & (NSLOT-1);
                }
                if (!done) {
                    int k = atomicAdd(&s_ovfcnt, 1);
                    s_ovf[k]  = make_int2(vox, h);
                    s_ovfw[k] = wgt;
                    last_vox = -1;
                }
            }
        }
    }

    __syncthreads();

    float freg[FHh];
    #pragma unroll
    for (int h = 0; h < FHh; ++h) freg[h] = s_feat[(h << 6) + lane];

    const int nocc = s_nslot;
    for (int e = wv; e < nocc; e += 4) {
        int slot = s_list[e];
        int vox  = s_keys[slot];
        float acc = 0.0f;
        #pragma unroll
        for (int h = 0; h < FHh; ++h)
            acc += s_coef[slot*17 + h] * freg[h];
        atomicAdd(&ws[(size_t)vox * CC + lane], acc);
        if (lane == 0) bmapT[vox >> 6] = 1;
    }
    const int novf = s_ovfcnt;
    for (int e = wv; e < novf; e += 4) {
        int vox = s_ovf[e].x, h = s_ovf[e].y;
        atomicAdd(&ws[(size_t)vox * CC + lane], s_ovfw[e] * freg[h]);
        if (lane == 0) bmapT[vox >> 6] = 1;
    }
}

__global__ __launch_bounds__(256)
void lss_transpose_g(const float* __restrict__ ws,
                     const unsigned char* __restrict__ bmapT,
                     float* __restrict__ out)
{
    __shared__ float tile[CC][65];
    const int blk  = blockIdx.x;
    const int bz   = blk / 625;
    const int xy0  = (blk % 625) * 64;
    const int t    = threadIdx.x;
    const int lane = t & 63;
    const int wv   = t >> 6;

    float* dst = out + (size_t)bz * CC * XYg + xy0;
    if (bmapT[blk] == 0) {
        const float4 z = make_float4(0.f, 0.f, 0.f, 0.f);
        #pragma unroll
        for (int rep = 0; rep < 4; ++rep) {
            int c = (wv << 4) + (rep << 2) + (lane >> 4);
            int q = lane & 15;
            ((float4*)(dst + (size_t)c * XYg))[q] = z;
        }
        return;
    }

    const int vb = bz * XYg + xy0;
    const float4* src = (const float4*)(ws + (size_t)vb * CC);
    #pragma unroll
    for (int rep = 0; rep < 4; ++rep) {
        int idx = (wv << 8) + (rep << 6) + lane;
        int xyl = idx >> 4;
        int c4  = idx & 15;
        float4 v = src[idx];
        tile[(c4<<2)+0][xyl] = v.x;
        tile[(c4<<2)+1][xyl] = v.y;
        tile[(c4<<2)+2][xyl] = v.z;
        tile[(c4<<2)+3][xyl] = v.w;
    }
    __syncthreads();
    #pragma unroll
    for (int rep = 0; rep < 4; ++rep) {
        int c   = (wv << 4) + (rep << 2) + (lane >> 4);
        int xy4 = lane & 15;
        float4 v = make_float4(tile[c][(xy4<<2)+0], tile[c][(xy4<<2)+1],
                               tile[c][(xy4<<2)+2], tile[c][(xy4<<2)+3]);
        ((float4*)(dst + (size_t)c * XYg))[xy4] = v;
    }
}

// ---------------- fallback (tiny ws): zero out + direct atomics -------------
__global__ __launch_bounds__(256)
void lss_scatter_direct(const float* __restrict__ xf,
                        const float* __restrict__ rots,
                        const float* __restrict__ trans,
                        const float* __restrict__ intr,
                        const float* __restrict__ prots,
                        const float* __restrict__ ptrans,
                        float* __restrict__ acc)
{
    const int wid  = blockIdx.x * 4 + (threadIdx.x >> 6);
    const int lane = threadIdx.x & 63;
    if (wid >= NPIX) return;
    int w  = wid % FWw;
    int t1 = wid / FWw;
    int h  = t1 % FHh; t1 /= FHh;
    int n  = t1 % NN;
    int b  = t1 / NN;
    const int cam = b*NN + n;

    double K9[9], P9[9], R9[9];
    #pragma unroll
    for (int i = 0; i < 9; ++i) {
        K9[i] = (double)intr [cam*9 + i];
        P9[i] = (double)prots[cam*9 + i];
        R9[i] = (double)rots [cam*9 + i];
    }
    double Kinv[9], Pinv[9];
    inv3x3d(K9, Kinv);
    inv3x3d(P9, Pinv);
    double M[9];
    #pragma unroll
    for (int i = 0; i < 3; ++i)
        #pragma unroll
        for (int j = 0; j < 3; ++j)
            M[i*3+j] = R9[i*3+0]*Kinv[0*3+j] + R9[i*3+1]*Kinv[1*3+j] + R9[i*3+2]*Kinv[2*3+j];
    const double tx  = (double)trans [cam*3+0], ty  = (double)trans [cam*3+1], tz  = (double)trans [cam*3+2];
    const double ptx = (double)ptrans[cam*3+0], pty = (double)ptrans[cam*3+1], ptz = (double)ptrans[cam*3+2];

    const size_t pixoff = (size_t)cam * NCH * FHh * FWw + (size_t)h * FWw + w;
    float logit = (lane < DD) ? xf[pixoff + (size_t)lane * (FHh*FWw)] : -INFINITY;
    float mx = logit;
    #pragma unroll
    for (int off = 32; off; off >>= 1) mx = fmaxf(mx, __shfl_xor(mx, off));
    float ex = (lane < DD) ? expf(logit - mx) : 0.0f;
    float sm = ex;
    #pragma unroll
    for (int off = 32; off; off >>= 1) sm += __shfl_xor(sm, off);
    const float wgt = ex / sm;

    int baddr = -1;
    if (lane < DD) {
        double dz = 4.0 + (double)lane;
        double xs = (double)w * (703.0/43.0);
        double ys = (double)h * 17.0;
        double px = xs - ptx, py = ys - pty, pz = dz - ptz;
        double qx = Pinv[0]*px + Pinv[1]*py + Pinv[2]*pz;
        double qy = Pinv[3]*px + Pinv[4]*py + Pinv[5]*pz;
        double qz = Pinv[6]*px + Pinv[7]*py + Pinv[8]*pz;
        qx *= qz; qy *= qz;
        double gx = M[0]*qx + M[1]*qy + M[2]*qz + tx;
        double gy = M[3]*qx + M[4]*qy + M[5]*qz + ty;
        double gz = M[6]*qx + M[7]*qy + M[8]*qz + tz;
        double fx = floor((gx + 50.0) / 0.5);
        double fy = floor((gy + 50.0) / 0.5);
        double fz = floor((gz + 10.0) / 20.0);
        if (fx >= 0.0 && fx < (double)NXg &&
            fy >= 0.0 && fy < (double)NYg &&
            fz >= 0.0 && fz < (double)NZg) {
            int ix = (int)fx, iy = (int)fy, iz = (int)fz;
            int bz = b*NZg + iz;
            baddr = bz * (CC*XYg) + ix*NYg + iy;
        }
    }

    const float f = xf[pixoff + (size_t)(DD + lane) * (FHh*FWw)];
    for (int d = 0; d < DD; ++d) {
        int   a  = __shfl(baddr, d);
        float wd = __shfl(wgt,   d);
        if (a >= 0) atomicAdd(&acc[(size_t)a + (size_t)lane * XYg], wd * f);
    }
}

extern "C" void kernel_launch(void* const* d_in, const int* in_sizes, int n_in,
                              void* d_out, int out_size, void* d_ws, size_t ws_size,
                              hipStream_t stream) {
    const float* xf     = (const float*)d_in[0];
    const float* rots   = (const float*)d_in[1];
    const float* trans  = (const float*)d_in[2];
    const float* intr   = (const float*)d_in[3];
    const float* prots  = (const float*)d_in[4];
    const float* ptrans = (const float*)d_in[5];
    float* out = (float*)d_out;

    if (ws_size >= (size_t)WS_NEED) {
        char* wsb = (char*)d_ws;
        float* ws = (float*)(wsb + WSV_OFF);
        unsigned char* bmapv = (unsigned char*)(wsb + BMAPV_OFF);
        unsigned char* bmapT = (unsigned char*)(wsb + BMAPT_OFF);

        int occ = 0;
        hipError_t qe = hipOccupancyMaxActiveBlocksPerMultiprocessor(
            &occ, reinterpret_cast<const void*>(&lss_fused), 256, 0);
        bool coop_ok = (qe == hipSuccess) && (occ >= 5);

        if (coop_ok) {
            // zero the 160 KB per-voxel byte map only
            lss_zero<<<dim3(64), dim3(256), 0, stream>>>(
                (float4*)bmapv, NVOX/16);
            void* kargs[] = { (void*)&xf, (void*)&rots, (void*)&trans,
                              (void*)&intr, (void*)&prots, (void*)&ptrans,
                              (void*)&ws, (void*)&bmapv, (void*)&out };
            hipError_t le = hipLaunchCooperativeKernel(
                (void*)lss_fused, dim3(NCOL), dim3(256), kargs, 0, stream);
            if (le == hipSuccess) return;
        }
        // proven R15 path
        lss_zero<<<dim3(2048), dim3(256), 0, stream>>>(
            (float4*)wsb, WS_NEED/16);
        lss_scatter_dedup<<<dim3(NCOL), dim3(256), 0, stream>>>(
            xf, rots, trans, intr, prots, ptrans, ws, bmapT);
        lss_transpose_g<<<dim3(NTILE), dim3(256), 0, stream>>>(
            ws, bmapT, out);
    } else {
        lss_zero<<<dim3(2048), dim3(256), 0, stream>>>(
            (float4*)out, (BB*NZg*XYg*CC)/4);
        lss_scatter_direct<<<dim3((NPIX + 3) / 4), dim3(256), 0, stream>>>(
            xf, rots, trans, intr, prots, ptrans, out);
    }
}